// Round 1
// 190.984 us; speedup vs baseline: 1.0585x; 1.0585x over previous
//
#include <hip/hip_runtime.h>
#include <limits.h>
#include <math.h>
#include <stdint.h>

#define WOS_ZERO_TOL 1e-6f
#define STRIDE 57   // odd stride: 16 channel rows start on distinct banks

// One wave (64 lanes) per pixel.
// Phase 1 (per nc): lane d owns candidate d (d<27: patch value, d>=27:
//   negated). Stable descending rank via u64 key (ordered_float :: 63-lane)
//   — bit-exact vs jnp stable argsort. Keys broadcast through LDS; rank loop
//   reads key PAIRS via ds_read_b128 (27 issues instead of 54); per pair the
//   VALU cost is 2x (v_cmp_gt_u64 + v_addc).
//   NEW: no s_mx value scatter. Phase 1 stores only the 1-byte rank per
//   (nc, lane); the winner's value is re-derived bit-exactly in phase 3 as
//   inp + mask[nc][lane] (single f32 add, identical operands/op as phase 1).
//   This cuts LDS 31232 -> 20224 B/block => 8 blocks/CU (was 5) => 100% of
//   the 32-wave/CU slots instead of 52% occupancy.
// Phase 2 (transposed): lane nc = lane&15 walks the 54 sorted weights once —
//   sequential f32 adds, association order identical to np.cumsum.
//   rstar = last r with (w>0 && acc<=bias). First-nz fallback moved to a
//   never-taken divergent loop (first nz weight <= 1 < bias ~= 13.5), so the
//   hot loop is read+add+2cmp+cndmask only. Lanes<16 publish rstar.
// Phase 3: per nc, all lanes read rstar (uniform LDS broadcast) and their
//   stored rank byte; the unique lane with rank==rstar recomputes its value
//   and writes it to s_out; lanes<16 do one coalesced 64B store.
// s_r/s_out live in the dead s_key region (phase 1 finished with it; same
//   wave, in-order LDS). asm memory fences pin the type-punned ordering
//   against TBAA-based reordering.
__global__ __launch_bounds__(256, 8) void wos_kernel(
    const float* __restrict__ x,       // (8,3,64,64)
    const float* __restrict__ mask,    // (16,54)
    const float* __restrict__ weight,  // (16,54)
    const float* __restrict__ bias,    // (16,1)
    float* __restrict__ out)           // flat: [pixel*16 + nc]
{
    __shared__ float s_ws[4][16][STRIDE];                    // 14592 B
    __shared__ __align__(16) unsigned long long s_key[4][64]; //  2048 B
    __shared__ unsigned char s_rank[4][16][56];              //  3584 B
    // total 20224 B -> 8 blocks/CU

    const int lane = threadIdx.x & 63;
    const int wid  = threadIdx.x >> 6;
    const int p    = blockIdx.x * 4 + wid;   // pixel in [0, 32768)
    const int b    = p >> 12;
    const int l    = p & 4095;
    const int h    = l >> 6;
    const int w    = l & 63;

    // Gather this lane's patch value (zero padding at borders).
    float inp = 0.0f;
    if (lane < 54) {
        int dm  = (lane < 27) ? lane : lane - 27;
        int c   = dm / 9;
        int rem = dm - 9 * c;
        int di  = rem / 3;
        int dj  = rem - 3 * di;
        int hh  = h + di - 1;
        int ww  = w + dj - 1;
        if (hh >= 0 && hh < 64 && ww >= 0 && ww < 64) {
            float v = x[((b * 3 + c) << 12) + (hh << 6) + ww];
            inp = (lane < 27) ? v : -v;
        }
    }

    const uint32_t inv_lane = (uint32_t)(63 - lane);
    const int midx = (lane < 54) ? lane : 0;   // clamped index: branchless loads

    // Software prefetch of next nc's mask/weight (L1-hot, hides load latency
    // even before occupancy kicks in).
    float mk_next = mask[midx];
    float wv_next = weight[midx];

    // ---- Phase 1: rank via LDS-broadcast key-pair compares, store ws+rank --
    #pragma unroll 1
    for (int nc = 0; nc < 16; ++nc) {
        const float mk = mk_next;
        const float wv = wv_next;
        if (nc < 15) {
            mk_next = mask[(nc + 1) * 54 + midx];
            wv_next = weight[(nc + 1) * 54 + midx];
        }
        const float mxv  = inp + mk;               // idle lanes: junk, unused
        const float wsel = (wv > WOS_ZERO_TOL) ? wv : 0.0f;

        // Order-preserving uint32 map of float order (no NaNs here).
        const int      bits = __float_as_int(mxv);
        const uint32_t ob   = (uint32_t)(bits ^ ((bits >> 31) | 0x80000000));
        // 64-bit stable key: value major, (63-lane) minor -> distinct keys,
        // strict > reproduces jnp's stable descending argsort exactly.
        const uint64_t myk  = ((uint64_t)ob << 32) | inv_lane;

        s_key[wid][lane] = myk;
        // Fence: ds_read_b128 below is a different TBAA type than the u64
        // store; keep program order (store must precede the broadcast reads).
        asm volatile("" ::: "memory");

        // rank = #{dp in 0..53 : key_dp > key_mine}. Uniform-address LDS
        // b128 reads broadcast two keys per issue.
        const ulonglong2* kp = (const ulonglong2*)(&s_key[wid][0]);
        uint32_t r0 = 0, r1 = 0;
        #pragma unroll
        for (int i = 0; i < 27; ++i) {
            ulonglong2 kk = kp[i];
            r0 += (kk.x > myk) ? 1u : 0u;
            r1 += (kk.y > myk) ? 1u : 0u;
        }
        const uint32_t rank = r0 + r1;

        // Active lanes get distinct ranks covering exactly 0..53.
        if (lane < 54) {
            s_ws[wid][nc][rank]   = wsel;
            s_rank[wid][nc][lane] = (unsigned char)rank;
        }
    }

    // Phase 1 is done with s_key: reuse its space for phase-2/3 scratch.
    asm volatile("" ::: "memory");
    int*   s_r   = (int*)(&s_key[wid][0]);     // 16 ints  (bytes 0..63)
    float* s_out = (float*)(&s_key[wid][16]);  // 16 floats (bytes 128..191)

    // ---- Phase 2: transposed sequential scan, lane = channel ----
    {
        const int   ncp = lane & 15;      // lanes 16..63 run redundant copies
        const float bv  = bias[ncp];
        float acc   = 0.0f;
        int   rstar = -1;
        #pragma unroll
        for (int r = 0; r < 54; ++r) {
            float wr = s_ws[wid][ncp][r];
            acc += wr;                                  // exact np.cumsum order
            rstar = (wr > 0.0f && acc <= bv) ? r : rstar;  // last nz, acc<=bias
        }
        if (rstar < 0) {                  // fallback: first nz (never taken:
            #pragma unroll 1              // first nz weight <=1 < bias~13.5)
            for (int r = 53; r >= 0; --r) {
                float wr = s_ws[wid][ncp][r];
                rstar = (wr > 0.0f) ? r : rstar;
            }
            if (rstar < 0) rstar = 0;
        }
        if (lane < 16) s_r[ncp] = rstar;
    }

    // ---- Phase 3: winner lane re-derives its value, coalesced store ----
    {
        #pragma unroll 1
        for (int nc = 0; nc < 16; ++nc) {
            const int   rk = (int)s_rank[wid][nc][midx];
            const int   rs = s_r[nc];                    // uniform broadcast
            const float mk = mask[nc * 54 + midx];       // L1-hot reload
            if (lane < 54 && rk == rs)
                s_out[nc] = inp + mk;    // bit-exact re-derivation of mxv
        }
        if (lane < 16) out[p * 16 + lane] = s_out[lane];
    }
}

extern "C" void kernel_launch(void* const* d_in, const int* in_sizes, int n_in,
                              void* d_out, int out_size, void* d_ws, size_t ws_size,
                              hipStream_t stream) {
    const float* x      = (const float*)d_in[0];
    const float* mask   = (const float*)d_in[1];
    const float* weight = (const float*)d_in[2];
    const float* bias   = (const float*)d_in[3];
    float* out = (float*)d_out;

    // 32768 pixels, 4 waves (pixels) per 256-thread block -> 8192 blocks
    wos_kernel<<<dim3(8192), dim3(256), 0, stream>>>(x, mask, weight, bias, out);
}